// Round 12
// baseline (317.110 us; speedup 1.0000x reference)
//
#include <hip/hip_runtime.h>

#define BATCH 2048

typedef _Float16 f16;
typedef __attribute__((ext_vector_type(8))) f16 f16x8;
typedef __attribute__((ext_vector_type(4))) float f32x4;

__device__ inline unsigned short f2h(float f) {
  union { f16 h; unsigned short u; } v;
  v.h = (f16)f;
  return v.u;
}

// -------------------------------------------------- conv1 + bias + relu + bn1 stats
// out layout: [b][pos(256)][co(32)]; stats -> bucketed [8][2][128]
__global__ __launch_bounds__(256) void k_conv1(
    const float* __restrict__ x, const float* __restrict__ w,
    const float* __restrict__ bias, float* __restrict__ out,
    float* __restrict__ stat) {
  __shared__ float xs[324];
  __shared__ float wsm[288];
  __shared__ float red[512];
  int b = blockIdx.x, t = threadIdx.x;
  const float* xb = x + (size_t)b * 324;
  for (int i = t; i < 324; i += 256) xs[i] = xb[i];
  for (int i = t; i < 288; i += 256) wsm[i] = w[i];
  __syncthreads();
  int co = t & 31, pp = t >> 5;
  float wv[9];
#pragma unroll
  for (int k = 0; k < 9; k++) wv[k] = wsm[co * 9 + k];
  float bb = bias[co];
  float sp = 0.0f, qp = 0.0f;
  float* ob = out + (size_t)b * 8192;
  for (int i = 0; i < 32; i++) {
    int pos = (i << 3) + pp;
    int ho = pos >> 4, wo = pos & 15;
    float a = bb;
#pragma unroll
    for (int ki = 0; ki < 3; ki++)
#pragma unroll
      for (int kj = 0; kj < 3; kj++)
        a = fmaf(xs[(ho + ki) * 18 + wo + kj], wv[ki * 3 + kj], a);
    a = fmaxf(a, 0.0f);
    ob[pos * 32 + co] = a;
    sp += a;
    qp = fmaf(a, a, qp);
  }
  red[t] = sp;
  red[256 + t] = qp;
  __syncthreads();
  if (t < 32) {
    float S = 0.0f, Q = 0.0f;
#pragma unroll
    for (int r = 0; r < 8; r++) {
      S += red[r * 32 + t];
      Q += red[256 + r * 32 + t];
    }
    int bk = (b & 7) * 256;
    atomicAdd(stat + bk + t, S);
    atomicAdd(stat + bk + 128 + t, Q);
  }
}

// ------------------------------------------------------------ weight prep
__global__ __launch_bounds__(256) void k_prep(
    const float* __restrict__ dc1, const float* __restrict__ dc2,
    const float* __restrict__ dc3, const float* __restrict__ ow1,
    const float* __restrict__ ow2, const float* __restrict__ ow3,
    unsigned short* __restrict__ wp1, unsigned short* __restrict__ wp2,
    unsigned short* __restrict__ wp3, unsigned short* __restrict__ w0p1,
    unsigned short* __restrict__ w0p2, unsigned short* __restrict__ w0p3) {
  int idx = blockIdx.x * 256 + threadIdx.x;
  if (idx < 239616) {
    int e = idx;
    const float* src; unsigned short* dst; int CIN, NCT, KS;
    if (e < 18432)      { src = dc1; dst = wp1; CIN = 32;  NCT = 4; KS = 1; }
    else if (e < 92160) { e -= 18432; src = dc2; dst = wp2; CIN = 64;  NCT = 8; KS = 2; }
    else                { e -= 92160; src = dc3; dst = wp3; CIN = 128; NCT = 8; KS = 4; }
    int j = e & 7, lane = (e >> 3) & 63;
    int rest = e >> 9;
    int ct = rest % NCT; rest /= NCT;
    int ks = rest % KS;
    int tap = rest / KS;
    int ci = ks * 32 + ((lane >> 4) << 3) + j;
    int co = ct * 16 + (lane & 15);
    dst[e] = f2h(src[((size_t)co * CIN + ci) * 9 + tap]);
  } else if (idx < 304128) {
    int e = idx - 239616;
    const float* src; unsigned short* dst; int CIN, KS;
    if (e < 9216)       { src = ow1; dst = w0p1; CIN = 32;  KS = 1; }
    else if (e < 27648) { e -= 9216;  src = ow2; dst = w0p2; CIN = 64;  KS = 2; }
    else                { e -= 27648; src = ow3; dst = w0p3; CIN = 128; KS = 4; }
    int j = e & 7, lane = (e >> 3) & 63;
    int rest = e >> 9;
    int ct = rest & 1; rest >>= 1;
    int ks = rest % KS;
    int tap = rest / KS;
    int ci = ks * 32 + ((lane >> 4) << 3) + j;
    int co = ct * 16 + (lane & 15);
    dst[e] = (co < 18) ? f2h(src[((size_t)co * CIN + ci) * 9 + tap])
                       : (unsigned short)0;
  }
}

// ------------------------------------------------------------ bilinear helper
template <int H, int W>
__device__ inline void bilin_setup(float py, float px, float& w00, float& w01,
                                   float& w10, float& w11, int& p00, int& p01,
                                   int& p10, int& p11, int CP) {
  float y0f = floorf(py), x0f = floorf(px);
  float wy = py - y0f, wx = px - x0f;
  int y0 = (int)y0f, x0 = (int)x0f, y1 = y0 + 1, x1 = x0 + 1;
  w00 = (1.0f - wy) * (1.0f - wx);
  w01 = (1.0f - wy) * wx;
  w10 = wy * (1.0f - wx);
  w11 = wy * wx;
  bool vy0 = (unsigned)y0 < (unsigned)H, vy1 = (unsigned)y1 < (unsigned)H;
  bool vx0 = (unsigned)x0 < (unsigned)W, vx1 = (unsigned)x1 < (unsigned)W;
  w00 = (vy0 && vx0) ? w00 : 0.0f;
  w01 = (vy0 && vx1) ? w01 : 0.0f;
  w10 = (vy1 && vx0) ? w10 : 0.0f;
  w11 = (vy1 && vx1) ? w11 : 0.0f;
  int yc0 = min(max(y0, 0), H - 1) * W, yc1 = min(max(y1, 0), H - 1) * W;
  int xc0 = min(max(x0, 0), W - 1),     xc1 = min(max(x1, 0), W - 1);
  p00 = (yc0 + xc0) * CP; p01 = (yc0 + xc1) * CP;
  p10 = (yc1 + xc0) * CP; p11 = (yc1 + xc1) * CP;
}

// build split-fp16 A fragment half (4 elems at slot g*4) from bilinear
#define BILIN4(ci_)                                                          \
  {                                                                          \
    float4 f00 = *(const float4*)&tile[p00 + (ci_)];                         \
    float4 f01 = *(const float4*)&tile[p01 + (ci_)];                         \
    float4 f10 = *(const float4*)&tile[p10 + (ci_)];                         \
    float4 f11 = *(const float4*)&tile[p11 + (ci_)];                         \
    float v0 = w00 * f00.x + w01 * f01.x + w10 * f10.x + w11 * f11.x;        \
    float v1 = w00 * f00.y + w01 * f01.y + w10 * f10.y + w11 * f11.y;        \
    float v2 = w00 * f00.z + w01 * f01.z + w10 * f10.z + w11 * f11.z;        \
    float v3 = w00 * f00.w + w01 * f01.w + w10 * f10.w + w11 * f11.w;        \
    ah[g * 4 + 0] = (f16)v0; al[g * 4 + 0] = (f16)(v0 - (float)ah[g * 4 + 0]); \
    ah[g * 4 + 1] = (f16)v1; al[g * 4 + 1] = (f16)(v1 - (float)ah[g * 4 + 1]); \
    ah[g * 4 + 2] = (f16)v2; al[g * 4 + 2] = (f16)(v2 - (float)ah[g * 4 + 2]); \
    ah[g * 4 + 3] = (f16)v3; al[g * 4 + 3] = (f16)(v3 - (float)ah[g * 4 + 3]); \
  }

// ------------------------------------------------------------ fused BN + offsetconv + deform conv, S=64
// Inline BN finalize (from bucketed stats of previous stage) + register-fragment
// MFMA pipeline. Fully unrolled tap loops for cross-tap ILP. 2 block barriers.
template <int CIN, int H, int W, int STRIDE, int HO, int WO, int COUT, int MINB>
__global__ __launch_bounds__(256, MINB) void k_dconv12(
    const float* __restrict__ in, const float* __restrict__ stp,
    const float* __restrict__ bng, const float* __restrict__ bnb, float invN,
    const unsigned short* __restrict__ w0p, const float* __restrict__ obias,
    const unsigned short* __restrict__ wp, float* __restrict__ out,
    float* __restrict__ stat) {
  constexpr int S   = HO * WO;          // 64
  constexpr int HW  = H * W;
  constexpr int CP  = CIN + 4;
  constexpr int NCT = COUT / 16;
  constexpr int KS  = CIN / 32;
  static_assert(S == 64, "geometry");

  __shared__ float tile[HW * CP];
  __shared__ float offs[18 * 64];
  __shared__ float scsh[2 * CIN];

  int b = blockIdx.x, t = threadIdx.x;

  // ---- inline BN finalize for this stage's input
  if (t < CIN) {
    float m = 0.0f, v = 0.0f;
#pragma unroll
    for (int j = 0; j < 8; j++) {
      m += stp[j * 256 + t];
      v += stp[j * 256 + 128 + t];
    }
    m *= invN;
    v = v * invN - m * m;
    float sc = rsqrtf(v + 1e-5f) * bng[t];
    scsh[t] = sc;
    scsh[CIN + t] = bnb[t] - m * sc;
  }
  __syncthreads();

  const float* inb = in + (size_t)b * CIN * HW;
  for (int i = t; i < HW * CIN / 4; i += 256) {
    int pos = i / (CIN / 4);
    int c4 = (i % (CIN / 4)) * 4;
    float4 v = *(const float4*)&inb[pos * CIN + c4];
    float4 sc = *(const float4*)&scsh[c4];
    float4 sh = *(const float4*)&scsh[CIN + c4];
    float4 o;
    o.x = fmaf(v.x, sc.x, sh.x);
    o.y = fmaf(v.y, sc.y, sh.y);
    o.z = fmaf(v.z, sc.z, sh.z);
    o.w = fmaf(v.w, sc.w, sh.w);
    *(float4*)&tile[pos * CP + c4] = o;
  }
  __syncthreads();
  // ======== everything below is wave-independent ========

  int lane = t & 63, w = t >> 6;
  int srow = lane & 15, q = lane >> 4;
  int s = w * 16 + srow;                // this lane's output row
  int ho_a = s / WO, wo_a = s % WO;

  // ---- phase 0: offset conv via MFMA, register A fragments (fully unrolled)
  {
    f32x4 oacc[2];
    oacc[0] = (f32x4){0.f, 0.f, 0.f, 0.f};
    oacc[1] = (f32x4){0.f, 0.f, 0.f, 0.f};
#pragma unroll
    for (int k = 0; k < 9; k++) {
      int y = ho_a * STRIDE - 1 + k / 3;
      int x = wo_a * STRIDE - 1 + k % 3;
      bool valid = ((unsigned)y < (unsigned)H) && ((unsigned)x < (unsigned)W);
      int pos = valid ? y * W + x : 0;
      const unsigned short* wk0 = w0p + (size_t)k * KS * 2 * 512;
#pragma unroll
      for (int ks = 0; ks < KS; ks++) {
        f16x8 av;
#pragma unroll
        for (int g = 0; g < 2; g++) {
          int ci = ks * 32 + q * 8 + g * 4;
          float4 f = *(const float4*)&tile[pos * CP + ci];
          av[g * 4 + 0] = (f16)(valid ? f.x : 0.0f);
          av[g * 4 + 1] = (f16)(valid ? f.y : 0.0f);
          av[g * 4 + 2] = (f16)(valid ? f.z : 0.0f);
          av[g * 4 + 3] = (f16)(valid ? f.w : 0.0f);
        }
#pragma unroll
        for (int ct = 0; ct < 2; ct++) {
          const f16x8 bv = *(const f16x8*)&wk0[(ks * 2 + ct) * 512 + lane * 8];
          oacc[ct] = __builtin_amdgcn_mfma_f32_16x16x32_f16(av, bv, oacc[ct], 0, 0, 0);
        }
      }
    }
#pragma unroll
    for (int ct = 0; ct < 2; ct++) {
      int co = ct * 16 + srow;
      if (co < 18) {
        float bb = obias[co];
#pragma unroll
        for (int r = 0; r < 4; r++)
          offs[co * 64 + w * 16 + q * 4 + r] = oacc[ct][r] + bb;
      }
    }
  }

  // ---- main loop over 9 taps (register A fragments; fully unrolled)
  f32x4 acc[NCT];
#pragma unroll
  for (int ct = 0; ct < NCT; ct++) acc[ct] = (f32x4){0.f, 0.f, 0.f, 0.f};

#pragma unroll
  for (int k = 0; k < 9; k++) {
    float dy = offs[(2 * k) * 64 + s];
    float dx = offs[(2 * k + 1) * 64 + s];
    float py = (float)(ho_a * STRIDE - 1 + k / 3) + dy;
    float px = (float)(wo_a * STRIDE - 1 + k % 3) + dx;
    float w00, w01, w10, w11;
    int p00, p01, p10, p11;
    bilin_setup<H, W>(py, px, w00, w01, w10, w11, p00, p01, p10, p11, CP);
    const unsigned short* wk = wp + (size_t)k * KS * NCT * 512;
#pragma unroll
    for (int ks = 0; ks < KS; ks++) {
      f16x8 ah, al;
#pragma unroll
      for (int g = 0; g < 2; g++) {
        int ci = ks * 32 + q * 8 + g * 4;
        BILIN4(ci);
      }
#pragma unroll
      for (int ct = 0; ct < NCT; ct++) {
        const f16x8 bv = *(const f16x8*)&wk[(ks * NCT + ct) * 512 + lane * 8];
        acc[ct] = __builtin_amdgcn_mfma_f32_16x16x32_f16(ah, bv, acc[ct], 0, 0, 0);
        acc[ct] = __builtin_amdgcn_mfma_f32_16x16x32_f16(al, bv, acc[ct], 0, 0, 0);
      }
    }
  }

  // ---- epilogue: relu + store + fused BN stats
  float* ob = out + (size_t)b * S * COUT;
  int bk = (b & 7) * 256;
#pragma unroll
  for (int ct = 0; ct < NCT; ct++) {
    int co = ct * 16 + srow;
    int sr = w * 16 + (q << 2);
    float sp = 0.0f, qp = 0.0f;
#pragma unroll
    for (int r = 0; r < 4; r++) {
      float v = fmaxf(acc[ct][r], 0.0f);
      ob[(sr + r) * COUT + co] = v;
      sp += v;
      qp = fmaf(v, v, qp);
    }
    sp += __shfl_xor(sp, 16, 64); sp += __shfl_xor(sp, 32, 64);
    qp += __shfl_xor(qp, 16, 64); qp += __shfl_xor(qp, 32, 64);
    if (q == 0) {
      atomicAdd(stat + bk + co, sp);
      atomicAdd(stat + bk + 128 + co, qp);
    }
  }
}

// ------------------------------------------------------------ stage-3 deform conv, S=16
// K-split waves, register fragments, inline BN finalize, fully unrolled taps.
__global__ __launch_bounds__(256, 4) void k_dconv3(
    const float* __restrict__ in, const float* __restrict__ stp,
    const float* __restrict__ bng, const float* __restrict__ bnb, float invN,
    const unsigned short* __restrict__ w0p, const float* __restrict__ obias,
    const unsigned short* __restrict__ wp, float* __restrict__ out,
    float* __restrict__ stat) {
  constexpr int CIN = 128, H = 8, W = 8, HO = 4, WO = 4, COUT = 128;
  constexpr int HW = 64, CP = CIN + 4;  // tile = 8448 floats (>= cred 4*64*33)
  constexpr int NCT = 8, KS = 4;

  __shared__ float tile[HW * CP];
  __shared__ float offs[288];
  __shared__ float scsh[256];

  int b = blockIdx.x, t = threadIdx.x;

  if (t < 128) {
    float m = 0.0f, v = 0.0f;
#pragma unroll
    for (int j = 0; j < 8; j++) {
      m += stp[j * 256 + t];
      v += stp[j * 256 + 128 + t];
    }
    m *= invN;
    v = v * invN - m * m;
    float sc = rsqrtf(v + 1e-5f) * bng[t];
    scsh[t] = sc;
    scsh[128 + t] = bnb[t] - m * sc;
  }
  __syncthreads();

  const float* inb = in + (size_t)b * CIN * HW;
  for (int i = t; i < HW * CIN / 4; i += 256) {
    int pos = i / (CIN / 4);
    int c4 = (i % (CIN / 4)) * 4;
    float4 v = *(const float4*)&inb[pos * CIN + c4];
    float4 sc = *(const float4*)&scsh[c4];
    float4 sh = *(const float4*)&scsh[128 + c4];
    float4 o;
    o.x = fmaf(v.x, sc.x, sh.x);
    o.y = fmaf(v.y, sc.y, sh.y);
    o.z = fmaf(v.z, sc.z, sh.z);
    o.w = fmaf(v.w, sc.w, sh.w);
    *(float4*)&tile[pos * CP + c4] = o;
  }
  for (int o = t; o < 288; o += 256) offs[o] = obias[o >> 4];
  __syncthreads();  // B1: tile + offs-bias ready

  int lane = t & 63, w = t >> 6;
  int srow = lane & 15, q = lane >> 4;
  int hoA = srow >> 2, woA = srow & 3;

  // ---- phase 0: offset conv partial over this wave's K-chunk (fully unrolled)
  {
    f32x4 oacc[2];
    oacc[0] = (f32x4){0.f, 0.f, 0.f, 0.f};
    oacc[1] = (f32x4){0.f, 0.f, 0.f, 0.f};
#pragma unroll
    for (int k = 0; k < 9; k++) {
      int y = hoA * 2 - 1 + k / 3;
      int x = woA * 2 - 1 + k % 3;
      bool valid = ((unsigned)y < (unsigned)H) && ((unsigned)x < (unsigned)W);
      int pos = valid ? y * W + x : 0;
      f16x8 av;
#pragma unroll
      for (int g = 0; g < 2; g++) {
        int ci = w * 32 + q * 8 + g * 4;
        float4 f = *(const float4*)&tile[pos * CP + ci];
        av[g * 4 + 0] = (f16)(valid ? f.x : 0.0f);
        av[g * 4 + 1] = (f16)(valid ? f.y : 0.0f);
        av[g * 4 + 2] = (f16)(valid ? f.z : 0.0f);
        av[g * 4 + 3] = (f16)(valid ? f.w : 0.0f);
      }
      const unsigned short* wk0 = w0p + ((size_t)k * 8 + w * 2) * 512;
#pragma unroll
      for (int ct = 0; ct < 2; ct++) {
        const f16x8 bv = *(const f16x8*)&wk0[ct * 512 + lane * 8];
        oacc[ct] = __builtin_amdgcn_mfma_f32_16x16x32_f16(av, bv, oacc[ct], 0, 0, 0);
      }
    }
#pragma unroll
    for (int ct = 0; ct < 2; ct++) {
      int co = ct * 16 + srow;
      if (co < 18) {
#pragma unroll
        for (int r = 0; r < 4; r++)
          atomicAdd(&offs[co * 16 + q * 4 + r], oacc[ct][r]);
      }
    }
  }
  __syncthreads();  // B2: all K-chunk partials summed into offs

  // ---- main loop: barrier-free, register fragments, partial C over ks=w
  f32x4 acc[NCT];
#pragma unroll
  for (int ct = 0; ct < NCT; ct++) acc[ct] = (f32x4){0.f, 0.f, 0.f, 0.f};

#pragma unroll
  for (int k = 0; k < 9; k++) {
    float dy = offs[(2 * k) * 16 + srow];
    float dx = offs[(2 * k + 1) * 16 + srow];
    float py = (float)(hoA * 2 - 1 + k / 3) + dy;
    float px = (float)(woA * 2 - 1 + k % 3) + dx;
    float w00, w01, w10, w11;
    int p00, p01, p10, p11;
    bilin_setup<H, W>(py, px, w00, w01, w10, w11, p00, p01, p10, p11, CP);
    f16x8 ah, al;
#pragma unroll
    for (int g = 0; g < 2; g++) {
      int ci = w * 32 + q * 8 + g * 4;
      BILIN4(ci);
    }
    const unsigned short* wk = wp + ((size_t)k * KS * NCT + w * NCT) * 512;
#pragma unroll
    for (int ct = 0; ct < NCT; ct++) {
      const f16x8 bv = *(const f16x8*)&wk[ct * 512 + lane * 8];
      acc[ct] = __builtin_amdgcn_mfma_f32_16x16x32_f16(ah, bv, acc[ct], 0, 0, 0);
      acc[ct] = __builtin_amdgcn_mfma_f32_16x16x32_f16(al, bv, acc[ct], 0, 0, 0);
    }
  }
  __syncthreads();  // B3: all waves done reading tile — safe to alias

  // ---- cross-wave C reduction (cred aliases tile; stride 33 = conflict-free)
  float* cred = tile;
  {
    float* slot = cred + (w * 64 + lane) * 33;
#pragma unroll
    for (int ct = 0; ct < NCT; ct++)
#pragma unroll
      for (int r = 0; r < 4; r++) slot[ct * 4 + r] = acc[ct][r];
  }
  __syncthreads();  // B4

  float* ob = out + (size_t)b * 16 * COUT;
  int bk = (b & 7) * 256;
#pragma unroll
  for (int ctl = 0; ctl < 2; ctl++) {
    int ct = w * 2 + ctl;
    int co = ct * 16 + srow;
    float sp = 0.0f, qp = 0.0f;
#pragma unroll
    for (int r = 0; r < 4; r++) {
      float v = cred[lane * 33 + ct * 4 + r] +
                cred[(64 + lane) * 33 + ct * 4 + r] +
                cred[(128 + lane) * 33 + ct * 4 + r] +
                cred[(192 + lane) * 33 + ct * 4 + r];
      v = fmaxf(v, 0.0f);
      ob[((q << 2) + r) * COUT + co] = v;
      sp += v;
      qp = fmaf(v, v, qp);
    }
    sp += __shfl_xor(sp, 16, 64); sp += __shfl_xor(sp, 32, 64);
    qp += __shfl_xor(qp, 16, 64); qp += __shfl_xor(qp, 32, 64);
    if (q == 0) {
      atomicAdd(stat + bk + co, sp);
      atomicAdd(stat + bk + 128 + co, qp);
    }
  }
}

// ------------------------------------------------------------ pool + fc (h4: [b][s][128])
// BN finalize inlined: thread c computes its own scale/shift from bucketed stats.
__global__ __launch_bounds__(128) void k_poolfc(
    const float* __restrict__ h4, const float* __restrict__ stp,
    const float* __restrict__ bng, const float* __restrict__ bnb, float invN,
    const float* __restrict__ fcw, const float* __restrict__ fcb,
    float* __restrict__ out) {
  __shared__ float pooled[128];
  int b = blockIdx.x;
  int c = threadIdx.x;
  float m = 0.0f, v = 0.0f;
#pragma unroll
  for (int j = 0; j < 8; j++) {
    m += stp[j * 256 + c];
    v += stp[j * 256 + 128 + c];
  }
  m *= invN;
  v = v * invN - m * m;
  float sc = rsqrtf(v + 1e-5f) * bng[c];
  float sh = bnb[c] - m * sc;
  const float* hb = h4 + (size_t)b * 2048;
  float sm = 0.0f;
#pragma unroll
  for (int s = 0; s < 16; s++) sm += hb[s * 128 + c];
  pooled[c] = fmaf(sm * (1.0f / 16.0f), sc, sh);
  __syncthreads();
  if (c < 10) {
    float acc = fcb[c];
#pragma unroll
    for (int i = 0; i < 128; i++) acc = fmaf(pooled[i], fcw[c * 128 + i], acc);
    out[(size_t)b * 10 + c] = acc;
  }
}

// ---------------------------------------------------------------- launch
extern "C" void kernel_launch(void* const* d_in, const int* in_sizes, int n_in,
                              void* d_out, int out_size, void* d_ws, size_t ws_size,
                              hipStream_t stream) {
  const float* x       = (const float*)d_in[0];
  const float* conv1_w = (const float*)d_in[1];
  const float* conv1_b = (const float*)d_in[2];
  const float* bn1_g   = (const float*)d_in[3];
  const float* bn1_b   = (const float*)d_in[4];
  const float* off1_w  = (const float*)d_in[5];
  const float* off1_b  = (const float*)d_in[6];
  const float* dc1_w   = (const float*)d_in[7];
  const float* bn2_g   = (const float*)d_in[8];
  const float* bn2_b   = (const float*)d_in[9];
  const float* off2_w  = (const float*)d_in[10];
  const float* off2_b  = (const float*)d_in[11];
  const float* dc2_w   = (const float*)d_in[12];
  const float* bn3_g   = (const float*)d_in[13];
  const float* bn3_b   = (const float*)d_in[14];
  const float* off3_w  = (const float*)d_in[15];
  const float* off3_b  = (const float*)d_in[16];
  const float* dc3_w   = (const float*)d_in[17];
  const float* bn4_g   = (const float*)d_in[18];
  const float* bn4_b   = (const float*)d_in[19];
  const float* fc_w    = (const float*)d_in[20];
  const float* fc_b    = (const float*)d_in[21];
  float* out = (float*)d_out;

  float* wsf = (float*)d_ws;
  // region A: h1 [2048][256][32] / h3 [2048][64][128] alias — 16777216 floats
  float* h1 = wsf;
  float* h3 = wsf;
  // region B: h2 [2048][64][64] / h4 [2048][16][128] alias — 8388608 floats
  float* h2 = wsf + 16777216;
  float* h4 = wsf + 16777216;
  float* wbase = wsf + 25165824;
  unsigned short* wp1  = (unsigned short*)wbase;  // fp16 dc packs (239616 ushorts)
  unsigned short* wp2  = wp1 + 18432;
  unsigned short* wp3  = wp2 + 73728;
  unsigned short* w0p1 = wp3 + 147456;            // fp16 offset packs (64512 ushorts)
  unsigned short* w0p2 = w0p1 + 9216;
  unsigned short* w0p3 = w0p2 + 18432;
  float* stat0 = wbase + 152064;                  // bucketed stats [8][2][128] x 4
  float* stat1 = stat0 + 2048;
  float* stat2 = stat1 + 2048;
  float* stat3 = stat2 + 2048;

  hipMemsetAsync(stat0, 0, 8192 * sizeof(float), stream);
  k_prep<<<1188, 256, 0, stream>>>(dc1_w, dc2_w, dc3_w, off1_w, off2_w, off3_w,
                                   wp1, wp2, wp3, w0p1, w0p2, w0p3);

  // stage 1
  k_conv1<<<BATCH, 256, 0, stream>>>(x, conv1_w, conv1_b, h1, stat0);
  k_dconv12<32, 16, 16, 2, 8, 8, 64, 3><<<BATCH, 256, 0, stream>>>(
      h1, stat0, bn1_g, bn1_b, 1.0f / 524288.0f, w0p1, off1_b, wp1, h2, stat1);

  // stage 2
  k_dconv12<64, 8, 8, 1, 8, 8, 128, 4><<<BATCH, 256, 0, stream>>>(
      h2, stat1, bn2_g, bn2_b, 1.0f / 131072.0f, w0p2, off2_b, wp2, h3, stat2);

  // stage 3
  k_dconv3<<<BATCH, 256, 0, stream>>>(
      h3, stat2, bn3_g, bn3_b, 1.0f / 131072.0f, w0p3, off3_b, wp3, h4, stat3);

  // stage 4
  k_poolfc<<<BATCH, 128, 0, stream>>>(h4, stat3, bn4_g, bn4_b, 1.0f / 32768.0f,
                                      fc_w, fc_b, out);
}